// Round 3
// baseline (984.232 us; speedup 1.0000x reference)
//
#include <hip/hip_runtime.h>
#include <math.h>

#define LB256 __launch_bounds__(256)

#define NB_SHIFT 8
#define NB_ROWS  (1 << NB_SHIFT)   // 256 rows per bucket
#define GA 512                     // blocks for hist/bucket-scatter passes
#define SCAN_CHUNK 2048            // row-level scan chunk (N <= 64*2048)

// ---------------- CSR build: counting sort, two-phase ----------------

// A1: per-row degree (global atomics) + per-(bucket,block) histogram
__global__ LB256 void hist_kernel(const int* __restrict__ row, int E, int nb, int chunk,
                                  int* __restrict__ cnt, int* __restrict__ countmat) {
    __shared__ int lh[512];
    for (int b = threadIdx.x; b < nb; b += 256) lh[b] = 0;
    __syncthreads();
    int beg = blockIdx.x * chunk;
    int end = min(E, beg + chunk);
    for (int i = beg + threadIdx.x; i < end; i += 256) {
        int r = row[i];
        atomicAdd(&cnt[r], 1);
        atomicAdd(&lh[r >> NB_SHIFT], 1);
    }
    __syncthreads();
    for (int b = threadIdx.x; b < nb; b += 256)
        countmat[b * gridDim.x + blockIdx.x] = lh[b];
}

// exclusive scan of countmat[M] -> off[M], off[M]=E.  single block, 1024 threads.
__global__ __launch_bounds__(1024) void scan_matrix_kernel(const int* __restrict__ countmat,
                                                           int M, int total,
                                                           int* __restrict__ off) {
    __shared__ int s[1024];
    int t = threadIdx.x;
    int per = (M + 1023) >> 10;
    int base = t * per;
    int sum = 0;
    for (int k = 0; k < per; ++k) {
        int idx = base + k;
        if (idx < M) sum += countmat[idx];
    }
    s[t] = sum;
    __syncthreads();
    for (int o = 1; o < 1024; o <<= 1) {
        int v = (t >= o) ? s[t - o] : 0;
        __syncthreads();
        s[t] += v;
        __syncthreads();
    }
    int run = s[t] - sum;  // exclusive prefix of this thread's chunk
    for (int k = 0; k < per; ++k) {
        int idx = base + k;
        if (idx < M) {
            off[idx] = run;
            run += countmat[idx];
        }
    }
    if (t == 1023) off[M] = total;
}

// A2: deterministic scatter into bucket-ordered tmp. entry = (col | rowlocal<<17, w)
__global__ LB256 void bucket_scatter_kernel(const int* __restrict__ row, const int* __restrict__ col,
                                            const float* __restrict__ w, const int* __restrict__ off,
                                            int E, int nb, int chunk, float2* __restrict__ tmp) {
    __shared__ int lc[512];
    __shared__ int loff[512];
    for (int b = threadIdx.x; b < nb; b += 256) {
        lc[b] = 0;
        loff[b] = off[b * gridDim.x + blockIdx.x];
    }
    __syncthreads();
    int beg = blockIdx.x * chunk;
    int end = min(E, beg + chunk);
    for (int i = beg + threadIdx.x; i < end; i += 256) {
        int r = row[i];
        int b = r >> NB_SHIFT;
        int lpos = atomicAdd(&lc[b], 1);
        unsigned pk = (unsigned)col[i] | ((unsigned)(r & (NB_ROWS - 1)) << 17);
        tmp[loff[b] + lpos] = make_float2(__int_as_float((int)pk), w[i]);
    }
}

// B: one block per bucket; scatter tmp -> csr at exact per-row positions.
__global__ LB256 void csr_scatter_kernel(const float2* __restrict__ tmp, const int* __restrict__ off,
                                         int nb, int G, int* __restrict__ wr,
                                         float2* __restrict__ csr) {
    int b = blockIdx.x;
    int s = off[b * G];
    int e = off[(b + 1) * G];  // off[M] = E covers last bucket
    int rbase = b << NB_SHIFT;
    const int stride = 256;
    int j = s + threadIdx.x;
    for (; j + 3 * stride < e; j += 4 * stride) {
        float2 c0 = tmp[j], c1 = tmp[j + stride], c2 = tmp[j + 2 * stride], c3 = tmp[j + 3 * stride];
        unsigned p0 = (unsigned)__float_as_int(c0.x);
        unsigned p1 = (unsigned)__float_as_int(c1.x);
        unsigned p2 = (unsigned)__float_as_int(c2.x);
        unsigned p3 = (unsigned)__float_as_int(c3.x);
        int q0 = atomicAdd(&wr[rbase + (int)(p0 >> 17)], 1);
        int q1 = atomicAdd(&wr[rbase + (int)(p1 >> 17)], 1);
        int q2 = atomicAdd(&wr[rbase + (int)(p2 >> 17)], 1);
        int q3 = atomicAdd(&wr[rbase + (int)(p3 >> 17)], 1);
        csr[q0] = make_float2(__int_as_float((int)(p0 & 0x1FFFF)), c0.y);
        csr[q1] = make_float2(__int_as_float((int)(p1 & 0x1FFFF)), c1.y);
        csr[q2] = make_float2(__int_as_float((int)(p2 & 0x1FFFF)), c2.y);
        csr[q3] = make_float2(__int_as_float((int)(p3 & 0x1FFFF)), c3.y);
    }
    for (; j < e; j += stride) {
        float2 c0 = tmp[j];
        unsigned p0 = (unsigned)__float_as_int(c0.x);
        int q0 = atomicAdd(&wr[rbase + (int)(p0 >> 17)], 1);
        csr[q0] = make_float2(__int_as_float((int)(p0 & 0x1FFFF)), c0.y);
    }
}

// ---------------- row-level scan (rowptr) ----------------

__global__ LB256 void scan_sum_kernel(const int* __restrict__ cnt, int n, int* __restrict__ blocksum) {
    int base = blockIdx.x * SCAN_CHUNK;
    int sum = 0;
    for (int i = threadIdx.x; i < SCAN_CHUNK; i += 256) {
        int idx = base + i;
        sum += (idx < n) ? cnt[idx] : 0;
    }
#pragma unroll
    for (int o = 32; o; o >>= 1) sum += __shfl_down(sum, o);
    __shared__ int ws[4];
    if ((threadIdx.x & 63) == 0) ws[threadIdx.x >> 6] = sum;
    __syncthreads();
    if (threadIdx.x == 0) blocksum[blockIdx.x] = ws[0] + ws[1] + ws[2] + ws[3];
}

__global__ void scan_offsets_kernel(const int* __restrict__ blocksum, int nbk,
                                    int* __restrict__ blockoff) {
    int lane = threadIdx.x;
    int v = (lane < nbk) ? blocksum[lane] : 0;
    int orig = v;
#pragma unroll
    for (int o = 1; o < 64; o <<= 1) {
        int u = __shfl_up(v, o);
        if (lane >= o) v += u;
    }
    if (lane < nbk) blockoff[lane] = v - orig;  // exclusive
}

__global__ LB256 void scan_scatter_kernel(const int* __restrict__ cnt, int n,
                                          const int* __restrict__ blockoff,
                                          int* __restrict__ rowptr, int* __restrict__ wr, int E) {
    int base = blockIdx.x * SCAN_CHUNK;
    int idx0 = base + threadIdx.x * 8;
    int vals[8];
    int s = 0;
#pragma unroll
    for (int k = 0; k < 8; ++k) {
        int id = idx0 + k;
        vals[k] = (id < n) ? cnt[id] : 0;
        s += vals[k];
    }
    int lane = threadIdx.x & 63, wid = threadIdx.x >> 6;
    int inc = s;
#pragma unroll
    for (int o = 1; o < 64; o <<= 1) {
        int u = __shfl_up(inc, o);
        if (lane >= o) inc += u;
    }
    __shared__ int wsum[4];
    if (lane == 63) wsum[wid] = inc;
    __syncthreads();
    int woff = 0;
    for (int i = 0; i < wid; ++i) woff += wsum[i];
    int excl = inc - s + woff + blockoff[blockIdx.x];
#pragma unroll
    for (int k = 0; k < 8; ++k) {
        int id = idx0 + k;
        if (id < n) { rowptr[id] = excl; wr[id] = excl; }
        excl += vals[k];
    }
    if (blockIdx.x == 0 && threadIdx.x == 0) rowptr[n] = E;
}

// ---------------- per-layer kernels ----------------

template <int FIN, int FOUT>
__global__ LB256 void transform_kernel(const float* __restrict__ h, const float* __restrict__ W,
                                       float* __restrict__ t, int n) {
    int i = blockIdx.x * blockDim.x + threadIdx.x;
    if (i >= n * FOUT) return;
    int v = i / FOUT;
    int f = i % FOUT;
    float s = 0.0f;
#pragma unroll
    for (int k = 0; k < FIN; ++k) s = fmaf(h[v * FIN + k], W[f * FIN + k], s);
    t[i] = s;
}

template <int F>
__global__ LB256 void agg_kernel(const int* __restrict__ rowptr, const float2* __restrict__ csr,
                                 const float* __restrict__ t, const float* __restrict__ b,
                                 float* __restrict__ h, int n) {
    constexpr int RPB = 256 / F;
    int lane = threadIdx.x % F;
    int grp = threadIdx.x / F;
    int v = blockIdx.x * RPB + grp;
    if (v >= n) return;
    int beg = rowptr[v], end = rowptr[v + 1];
    float bf = b[lane];
    float acc0 = 0.0f, acc1 = 0.0f;
    int j = beg;
    for (; j + 1 < end; j += 2) {
        float2 cw0 = csr[j];
        float2 cw1 = csr[j + 1];
        int c0 = __float_as_int(cw0.x);
        int c1 = __float_as_int(cw1.x);
        float m0 = fmaf(cw0.y, t[c0 * F + lane], bf);
        float m1 = fmaf(cw1.y, t[c1 * F + lane], bf);
        acc0 += (m0 > 0.0f) ? m0 : 0.01f * m0;
        acc1 += (m1 > 0.0f) ? m1 : 0.01f * m1;
    }
    if (j < end) {
        float2 cw = csr[j];
        int c = __float_as_int(cw.x);
        float m = fmaf(cw.y, t[c * F + lane], bf);
        acc0 += (m > 0.0f) ? m : 0.01f * m;
    }
    int deg = end - beg;
    float inv = (deg > 0) ? (1.0f / (float)deg) : 0.0f;
    float r = t[v * F + lane] + bf;
    r = (r > 0.0f) ? r : 0.01f * r;
    h[v * F + lane] = (acc0 + acc1) * inv + r;
}

// ---------------- head ----------------

__global__ LB256 void pool_kernel(const float* __restrict__ h, float* __restrict__ pool, int n) {
    __shared__ float ls[256];
    int f = threadIdx.x & 31;
    int grp = threadIdx.x >> 5;
    int gid = blockIdx.x * (blockDim.x >> 5) + grp;
    int ngrp = (blockDim.x >> 5) * gridDim.x;
    float s = 0.0f;
    for (int v = gid; v < n; v += ngrp) s += h[v * 32 + f];
    ls[threadIdx.x] = s;
    __syncthreads();
    if (threadIdx.x < 32) {
        float tot = 0.0f;
#pragma unroll
        for (int g = 0; g < 8; ++g) tot += ls[g * 32 + threadIdx.x];
        atomicAdd(&pool[threadIdx.x], tot);
    }
}

__global__ void head_kernel(const float* __restrict__ pool, const float* __restrict__ W7,
                            const float* __restrict__ b7, float* __restrict__ out, int n) {
    if (threadIdx.x != 0 || blockIdx.x != 0) return;
    float invn = 1.0f / (float)n;
    float l0 = b7[0], l1 = b7[1];
    for (int f = 0; f < 32; ++f) {
        float p = pool[f] * invn;
        l0 = fmaf(p, W7[f], l0);
        l1 = fmaf(p, W7[32 + f], l1);
    }
    float m = fmaxf(l0, l1);
    float lse = m + logf(expf(l0 - m) + expf(l1 - m));
    out[0] = l0 - lse;
    out[1] = l1 - lse;
}

// ---------------- launch ----------------

extern "C" void kernel_launch(void* const* d_in, const int* in_sizes, int n_in,
                              void* d_out, int out_size, void* d_ws, size_t ws_size,
                              hipStream_t stream) {
    const float* x  = (const float*)d_in[0];
    const int* edge = (const int*)d_in[1];
    const float* w  = (const float*)d_in[2];
    const float* W1 = (const float*)d_in[3];
    const float* b1 = (const float*)d_in[4];
    const float* W3 = (const float*)d_in[5];
    const float* b3 = (const float*)d_in[6];
    const float* W5 = (const float*)d_in[7];
    const float* b5 = (const float*)d_in[8];
    const float* W7 = (const float*)d_in[9];
    const float* b7 = (const float*)d_in[10];
    float* out = (float*)d_out;

    const int N = in_sizes[0] / 4;
    const int E = in_sizes[1] / 2;
    const int* row = edge;
    const int* col = edge + E;

    const int nb = (N + NB_ROWS - 1) >> NB_SHIFT;    // buckets of 256 rows
    const int G = GA;
    const int chunk = (E + G - 1) / G;
    const int M = nb * G;

    char* ws = (char*)d_ws;
    size_t off8 = 0;
    auto alloc = [&](size_t bytes) {
        void* p = ws + off8;
        off8 += (bytes + 255) & ~(size_t)255;
        return p;
    };
    int*    cnt      = (int*)alloc((size_t)N * 4);
    int*    rowptr   = (int*)alloc(((size_t)N + 1) * 4);
    int*    wr       = (int*)alloc((size_t)N * 4);
    int*    blocksum = (int*)alloc(256 * 4);
    int*    blockoff = (int*)alloc(256 * 4);
    int*    countmat = (int*)alloc((size_t)M * 4);
    int*    offm     = (int*)alloc(((size_t)M + 1) * 4);
    float*  pool     = (float*)alloc(32 * 4);
    float2* csr      = (float2*)alloc((size_t)E * 8);
    // big region: tmp during CSR build, then t+h during layers (E*8 == N*32*4*2 here; take max)
    size_t bigsz = (size_t)E * 8;
    size_t thsz  = (size_t)N * 32 * 4 * 2;
    char*  big   = (char*)alloc(bigsz > thsz ? bigsz : thsz);
    float2* tmp  = (float2*)big;
    float*  t    = (float*)big;
    float*  h    = (float*)(big + (size_t)N * 32 * 4);
    (void)ws_size;

    hipMemsetAsync(cnt, 0, (size_t)N * 4, stream);
    hipMemsetAsync(pool, 0, 32 * 4, stream);

    const int B = 256;
    const int nbk = (N + SCAN_CHUNK - 1) / SCAN_CHUNK;  // 49 for N=100000

    // CSR build (deterministic counting sort)
    hist_kernel<<<G, B, 0, stream>>>(row, E, nb, chunk, cnt, countmat);
    scan_matrix_kernel<<<1, 1024, 0, stream>>>(countmat, M, E, offm);
    scan_sum_kernel<<<nbk, B, 0, stream>>>(cnt, N, blocksum);
    scan_offsets_kernel<<<1, 64, 0, stream>>>(blocksum, nbk, blockoff);
    scan_scatter_kernel<<<nbk, B, 0, stream>>>(cnt, N, blockoff, rowptr, wr, E);
    bucket_scatter_kernel<<<G, B, 0, stream>>>(row, col, w, offm, E, nb, chunk, tmp);
    csr_scatter_kernel<<<nb, B, 0, stream>>>(tmp, offm, nb, G, wr, csr);

    // ---- block 1: 4 -> 8 ----
    transform_kernel<4, 8><<<(N * 8 + B - 1) / B, B, 0, stream>>>(x, W1, t, N);
    agg_kernel<8><<<(N + 31) / 32, B, 0, stream>>>(rowptr, csr, t, b1, h, N);

    // ---- block 2: 8 -> 16 ----
    transform_kernel<8, 16><<<(N * 16 + B - 1) / B, B, 0, stream>>>(h, W3, t, N);
    agg_kernel<16><<<(N + 15) / 16, B, 0, stream>>>(rowptr, csr, t, b3, h, N);

    // ---- block 3: 16 -> 32 ----
    transform_kernel<16, 32><<<(N * 32 + B - 1) / B, B, 0, stream>>>(h, W5, t, N);
    agg_kernel<32><<<(N + 7) / 8, B, 0, stream>>>(rowptr, csr, t, b5, h, N);

    // ---- head ----
    pool_kernel<<<256, B, 0, stream>>>(h, pool, N);
    head_kernel<<<1, 64, 0, stream>>>(pool, W7, b7, out, N);
}

// Round 4
// 622.608 us; speedup vs baseline: 1.5808x; 1.5808x over previous
//
#include <hip/hip_runtime.h>
#include <math.h>

#define LB256 __launch_bounds__(256)

#define NB_SHIFT 8
#define NB_ROWS  (1 << NB_SHIFT)   // 256 rows per bucket
#define GA 512                     // blocks for hist/bucket-scatter passes
#define CSR_SPLIT 4                // blocks per bucket in csr_scatter

// ---------------- generic hierarchical exclusive scan ----------------
// pass 1: per-block sums (chunk = 256*PT)
template <int PT>
__global__ LB256 void gscan_sum(const int* __restrict__ a, int n, int* __restrict__ bsum) {
    int base = blockIdx.x * (256 * PT);
    int sum = 0;
    for (int i = threadIdx.x; i < 256 * PT; i += 256) {
        int idx = base + i;
        sum += (idx < n) ? a[idx] : 0;
    }
#pragma unroll
    for (int o = 32; o; o >>= 1) sum += __shfl_down(sum, o);
    __shared__ int ws[4];
    if ((threadIdx.x & 63) == 0) ws[threadIdx.x >> 6] = sum;
    __syncthreads();
    if (threadIdx.x == 0) bsum[blockIdx.x] = ws[0] + ws[1] + ws[2] + ws[3];
}

// pass 2: single wave scans <=64 block sums -> exclusive offsets
__global__ void gscan_offsets(const int* __restrict__ bsum, int nbk, int* __restrict__ boff) {
    int lane = threadIdx.x;
    int v = (lane < nbk) ? bsum[lane] : 0;
    int orig = v;
#pragma unroll
    for (int o = 1; o < 64; o <<= 1) {
        int u = __shfl_up(v, o);
        if (lane >= o) v += u;
    }
    if (lane < nbk) boff[lane] = v - orig;  // exclusive
}

// pass 3: per-element exclusive prefix -> out1 (and optionally out2); out1[n] = total
template <int PT>
__global__ LB256 void gscan_scatter(const int* __restrict__ a, int n,
                                    const int* __restrict__ boff, int total,
                                    int* __restrict__ out1, int* __restrict__ out2) {
    int base = blockIdx.x * (256 * PT);
    int idx0 = base + threadIdx.x * PT;
    int vals[PT];
    int s = 0;
#pragma unroll
    for (int k = 0; k < PT; ++k) {
        int id = idx0 + k;
        vals[k] = (id < n) ? a[id] : 0;
        s += vals[k];
    }
    int lane = threadIdx.x & 63, wid = threadIdx.x >> 6;
    int inc = s;
#pragma unroll
    for (int o = 1; o < 64; o <<= 1) {
        int u = __shfl_up(inc, o);
        if (lane >= o) inc += u;
    }
    __shared__ int wsum[4];
    if (lane == 63) wsum[wid] = inc;
    __syncthreads();
    int woff = 0;
    for (int i = 0; i < wid; ++i) woff += wsum[i];
    int excl = inc - s + woff + boff[blockIdx.x];
#pragma unroll
    for (int k = 0; k < PT; ++k) {
        int id = idx0 + k;
        if (id < n) {
            out1[id] = excl;
            if (out2) out2[id] = excl;
        }
        excl += vals[k];
    }
    if (blockIdx.x == 0 && threadIdx.x == 0) out1[n] = total;
}

// ---------------- CSR build: counting sort, two-phase ----------------

// A1: per-row degree (global atomics) + per-(bucket,block) histogram
__global__ LB256 void hist_kernel(const int* __restrict__ row, int E, int nb, int chunk,
                                  int* __restrict__ cnt, int* __restrict__ countmat) {
    __shared__ int lh[512];
    for (int b = threadIdx.x; b < nb; b += 256) lh[b] = 0;
    __syncthreads();
    int beg = blockIdx.x * chunk;
    int end = min(E, beg + chunk);
    for (int i = beg + threadIdx.x; i < end; i += 256) {
        int r = row[i];
        atomicAdd(&cnt[r], 1);
        atomicAdd(&lh[r >> NB_SHIFT], 1);
    }
    __syncthreads();
    for (int b = threadIdx.x; b < nb; b += 256)
        countmat[b * gridDim.x + blockIdx.x] = lh[b];
}

// A2: deterministic scatter into bucket-ordered tmp. entry = (col | rowlocal<<17, w)
__global__ LB256 void bucket_scatter_kernel(const int* __restrict__ row, const int* __restrict__ col,
                                            const float* __restrict__ w, const int* __restrict__ off,
                                            int E, int nb, int chunk, float2* __restrict__ tmp) {
    __shared__ int lc[512];
    __shared__ int loff[512];
    for (int b = threadIdx.x; b < nb; b += 256) {
        lc[b] = 0;
        loff[b] = off[b * gridDim.x + blockIdx.x];
    }
    __syncthreads();
    int beg = blockIdx.x * chunk;
    int end = min(E, beg + chunk);
    for (int i = beg + threadIdx.x; i < end; i += 256) {
        int r = row[i];
        int b = r >> NB_SHIFT;
        int lpos = atomicAdd(&lc[b], 1);
        unsigned pk = (unsigned)col[i] | ((unsigned)(r & (NB_ROWS - 1)) << 17);
        tmp[loff[b] + lpos] = make_float2(__int_as_float((int)pk), w[i]);
    }
}

// B: CSR_SPLIT blocks per bucket; scatter tmp -> csr at exact per-row positions.
__global__ LB256 void csr_scatter_kernel(const float2* __restrict__ tmp, const int* __restrict__ off,
                                         int G, int* __restrict__ wr, float2* __restrict__ csr) {
    int b = blockIdx.x / CSR_SPLIT;
    int part = blockIdx.x % CSR_SPLIT;
    int s0 = off[b * G];
    int e0 = off[(b + 1) * G];
    int len = e0 - s0;
    int per = (len + CSR_SPLIT - 1) / CSR_SPLIT;
    int s = s0 + part * per;
    int e = min(e0, s + per);
    int rbase = b << NB_SHIFT;
    const int stride = 256;
    int j = s + threadIdx.x;
    for (; j + 3 * stride < e; j += 4 * stride) {
        float2 c0 = tmp[j], c1 = tmp[j + stride], c2 = tmp[j + 2 * stride], c3 = tmp[j + 3 * stride];
        unsigned p0 = (unsigned)__float_as_int(c0.x);
        unsigned p1 = (unsigned)__float_as_int(c1.x);
        unsigned p2 = (unsigned)__float_as_int(c2.x);
        unsigned p3 = (unsigned)__float_as_int(c3.x);
        int q0 = atomicAdd(&wr[rbase + (int)(p0 >> 17)], 1);
        int q1 = atomicAdd(&wr[rbase + (int)(p1 >> 17)], 1);
        int q2 = atomicAdd(&wr[rbase + (int)(p2 >> 17)], 1);
        int q3 = atomicAdd(&wr[rbase + (int)(p3 >> 17)], 1);
        csr[q0] = make_float2(__int_as_float((int)(p0 & 0x1FFFF)), c0.y);
        csr[q1] = make_float2(__int_as_float((int)(p1 & 0x1FFFF)), c1.y);
        csr[q2] = make_float2(__int_as_float((int)(p2 & 0x1FFFF)), c2.y);
        csr[q3] = make_float2(__int_as_float((int)(p3 & 0x1FFFF)), c3.y);
    }
    for (; j < e; j += stride) {
        float2 c0 = tmp[j];
        unsigned p0 = (unsigned)__float_as_int(c0.x);
        int q0 = atomicAdd(&wr[rbase + (int)(p0 >> 17)], 1);
        csr[q0] = make_float2(__int_as_float((int)(p0 & 0x1FFFF)), c0.y);
    }
}

// ---------------- per-layer kernels ----------------

template <int FIN, int FOUT>
__global__ LB256 void transform_kernel(const float* __restrict__ h, const float* __restrict__ W,
                                       float* __restrict__ t, int n) {
    int i = blockIdx.x * blockDim.x + threadIdx.x;
    if (i >= n * FOUT) return;
    int v = i / FOUT;
    int f = i % FOUT;
    float s = 0.0f;
#pragma unroll
    for (int k = 0; k < FIN; ++k) s = fmaf(h[v * FIN + k], W[f * FIN + k], s);
    t[i] = s;
}

template <int F>
__global__ LB256 void agg_kernel(const int* __restrict__ rowptr, const float2* __restrict__ csr,
                                 const float* __restrict__ t, const float* __restrict__ b,
                                 float* __restrict__ h, int n) {
    constexpr int RPB = 256 / F;
    int lane = threadIdx.x % F;
    int grp = threadIdx.x / F;
    int v = blockIdx.x * RPB + grp;
    if (v >= n) return;
    int beg = rowptr[v], end = rowptr[v + 1];
    float bf = b[lane];
    float acc0 = 0.0f, acc1 = 0.0f;
    int j = beg;
    for (; j + 1 < end; j += 2) {
        float2 cw0 = csr[j];
        float2 cw1 = csr[j + 1];
        int c0 = __float_as_int(cw0.x);
        int c1 = __float_as_int(cw1.x);
        float m0 = fmaf(cw0.y, t[c0 * F + lane], bf);
        float m1 = fmaf(cw1.y, t[c1 * F + lane], bf);
        acc0 += (m0 > 0.0f) ? m0 : 0.01f * m0;
        acc1 += (m1 > 0.0f) ? m1 : 0.01f * m1;
    }
    if (j < end) {
        float2 cw = csr[j];
        int c = __float_as_int(cw.x);
        float m = fmaf(cw.y, t[c * F + lane], bf);
        acc0 += (m > 0.0f) ? m : 0.01f * m;
    }
    int deg = end - beg;
    float inv = (deg > 0) ? (1.0f / (float)deg) : 0.0f;
    float r = t[v * F + lane] + bf;
    r = (r > 0.0f) ? r : 0.01f * r;
    h[v * F + lane] = (acc0 + acc1) * inv + r;
}

// ---------------- head ----------------

__global__ LB256 void pool_kernel(const float* __restrict__ h, float* __restrict__ pool, int n) {
    __shared__ float ls[256];
    int f = threadIdx.x & 31;
    int grp = threadIdx.x >> 5;
    int gid = blockIdx.x * (blockDim.x >> 5) + grp;
    int ngrp = (blockDim.x >> 5) * gridDim.x;
    float s = 0.0f;
    for (int v = gid; v < n; v += ngrp) s += h[v * 32 + f];
    ls[threadIdx.x] = s;
    __syncthreads();
    if (threadIdx.x < 32) {
        float tot = 0.0f;
#pragma unroll
        for (int g = 0; g < 8; ++g) tot += ls[g * 32 + threadIdx.x];
        atomicAdd(&pool[threadIdx.x], tot);
    }
}

__global__ void head_kernel(const float* __restrict__ pool, const float* __restrict__ W7,
                            const float* __restrict__ b7, float* __restrict__ out, int n) {
    if (threadIdx.x != 0 || blockIdx.x != 0) return;
    float invn = 1.0f / (float)n;
    float l0 = b7[0], l1 = b7[1];
    for (int f = 0; f < 32; ++f) {
        float p = pool[f] * invn;
        l0 = fmaf(p, W7[f], l0);
        l1 = fmaf(p, W7[32 + f], l1);
    }
    float m = fmaxf(l0, l1);
    float lse = m + logf(expf(l0 - m) + expf(l1 - m));
    out[0] = l0 - lse;
    out[1] = l1 - lse;
}

// ---------------- launch ----------------

extern "C" void kernel_launch(void* const* d_in, const int* in_sizes, int n_in,
                              void* d_out, int out_size, void* d_ws, size_t ws_size,
                              hipStream_t stream) {
    const float* x  = (const float*)d_in[0];
    const int* edge = (const int*)d_in[1];
    const float* w  = (const float*)d_in[2];
    const float* W1 = (const float*)d_in[3];
    const float* b1 = (const float*)d_in[4];
    const float* W3 = (const float*)d_in[5];
    const float* b3 = (const float*)d_in[6];
    const float* W5 = (const float*)d_in[7];
    const float* b5 = (const float*)d_in[8];
    const float* W7 = (const float*)d_in[9];
    const float* b7 = (const float*)d_in[10];
    float* out = (float*)d_out;

    const int N = in_sizes[0] / 4;
    const int E = in_sizes[1] / 2;
    const int* row = edge;
    const int* col = edge + E;

    const int nb = (N + NB_ROWS - 1) >> NB_SHIFT;    // buckets of 256 rows (391)
    const int G = GA;
    const int chunk = (E + G - 1) / G;
    const int M = nb * G;                            // ~200k

    char* ws = (char*)d_ws;
    size_t off8 = 0;
    auto alloc = [&](size_t bytes) {
        void* p = ws + off8;
        off8 += (bytes + 255) & ~(size_t)255;
        return p;
    };
    int*    cnt      = (int*)alloc((size_t)N * 4);
    int*    rowptr   = (int*)alloc(((size_t)N + 1) * 4);
    int*    wr       = (int*)alloc((size_t)N * 4);
    int*    bsumA    = (int*)alloc(256 * 4);
    int*    boffA    = (int*)alloc(256 * 4);
    int*    bsumB    = (int*)alloc(256 * 4);
    int*    boffB    = (int*)alloc(256 * 4);
    int*    countmat = (int*)alloc((size_t)M * 4);
    int*    offm     = (int*)alloc(((size_t)M + 1) * 4);
    float*  pool     = (float*)alloc(32 * 4);
    float2* csr      = (float2*)alloc((size_t)E * 8);
    size_t bigsz = (size_t)E * 8;
    size_t thsz  = (size_t)N * 32 * 4 * 2;
    char*  big   = (char*)alloc(bigsz > thsz ? bigsz : thsz);
    float2* tmp  = (float2*)big;
    float*  t    = (float*)big;
    float*  h    = (float*)(big + (size_t)N * 32 * 4);
    (void)ws_size;

    hipMemsetAsync(cnt, 0, (size_t)N * 4, stream);
    hipMemsetAsync(pool, 0, 32 * 4, stream);

    const int B = 256;
    const int nbkR = (N + 2047) / 2048;       // row scan blocks (PT=8)  -> 49
    const int nbkM = (M + 4095) / 4096;       // mat scan blocks (PT=16) -> 49

    // A1: histograms
    hist_kernel<<<G, B, 0, stream>>>(row, E, nb, chunk, cnt, countmat);

    // hierarchical scan of countmat -> offm (exclusive, offm[M]=E)
    gscan_sum<16><<<nbkM, B, 0, stream>>>(countmat, M, bsumB);
    gscan_offsets<<<1, 64, 0, stream>>>(bsumB, nbkM, boffB);
    gscan_scatter<16><<<nbkM, B, 0, stream>>>(countmat, M, boffB, E, offm, nullptr);

    // hierarchical scan of cnt -> rowptr & wr
    gscan_sum<8><<<nbkR, B, 0, stream>>>(cnt, N, bsumA);
    gscan_offsets<<<1, 64, 0, stream>>>(bsumA, nbkR, boffA);
    gscan_scatter<8><<<nbkR, B, 0, stream>>>(cnt, N, boffA, E, rowptr, wr);

    // A2 + B
    bucket_scatter_kernel<<<G, B, 0, stream>>>(row, col, w, offm, E, nb, chunk, tmp);
    csr_scatter_kernel<<<nb * CSR_SPLIT, B, 0, stream>>>(tmp, offm, G, wr, csr);

    // ---- block 1: 4 -> 8 ----
    transform_kernel<4, 8><<<(N * 8 + B - 1) / B, B, 0, stream>>>(x, W1, t, N);
    agg_kernel<8><<<(N + 31) / 32, B, 0, stream>>>(rowptr, csr, t, b1, h, N);

    // ---- block 2: 8 -> 16 ----
    transform_kernel<8, 16><<<(N * 16 + B - 1) / B, B, 0, stream>>>(h, W3, t, N);
    agg_kernel<16><<<(N + 15) / 16, B, 0, stream>>>(rowptr, csr, t, b3, h, N);

    // ---- block 3: 16 -> 32 ----
    transform_kernel<16, 32><<<(N * 32 + B - 1) / B, B, 0, stream>>>(h, W5, t, N);
    agg_kernel<32><<<(N + 7) / 8, B, 0, stream>>>(rowptr, csr, t, b5, h, N);

    // ---- head ----
    pool_kernel<<<256, B, 0, stream>>>(h, pool, N);
    head_kernel<<<1, 64, 0, stream>>>(pool, W7, b7, out, N);
}

// Round 5
// 436.297 us; speedup vs baseline: 2.2559x; 1.4270x over previous
//
#include <hip/hip_runtime.h>
#include <math.h>

#define LB256 __launch_bounds__(256)

#define NB_SHIFT 8
#define NB_ROWS  (1 << NB_SHIFT)   // 256 rows per bucket
#define GA 512                     // blocks for hist/bucket-scatter passes

// ---------------- generic hierarchical exclusive scan ----------------
template <int PT>
__global__ LB256 void gscan_sum(const int* __restrict__ a, int n, int* __restrict__ bsum) {
    int base = blockIdx.x * (256 * PT);
    int sum = 0;
    for (int i = threadIdx.x; i < 256 * PT; i += 256) {
        int idx = base + i;
        sum += (idx < n) ? a[idx] : 0;
    }
#pragma unroll
    for (int o = 32; o; o >>= 1) sum += __shfl_down(sum, o);
    __shared__ int ws[4];
    if ((threadIdx.x & 63) == 0) ws[threadIdx.x >> 6] = sum;
    __syncthreads();
    if (threadIdx.x == 0) bsum[blockIdx.x] = ws[0] + ws[1] + ws[2] + ws[3];
}

__global__ void gscan_offsets(const int* __restrict__ bsum, int nbk, int* __restrict__ boff) {
    int lane = threadIdx.x;
    int v = (lane < nbk) ? bsum[lane] : 0;
    int orig = v;
#pragma unroll
    for (int o = 1; o < 64; o <<= 1) {
        int u = __shfl_up(v, o);
        if (lane >= o) v += u;
    }
    if (lane < nbk) boff[lane] = v - orig;  // exclusive
}

template <int PT>
__global__ LB256 void gscan_scatter(const int* __restrict__ a, int n,
                                    const int* __restrict__ boff, int total,
                                    int* __restrict__ out1) {
    int base = blockIdx.x * (256 * PT);
    int idx0 = base + threadIdx.x * PT;
    int vals[PT];
    int s = 0;
#pragma unroll
    for (int k = 0; k < PT; ++k) {
        int id = idx0 + k;
        vals[k] = (id < n) ? a[id] : 0;
        s += vals[k];
    }
    int lane = threadIdx.x & 63, wid = threadIdx.x >> 6;
    int inc = s;
#pragma unroll
    for (int o = 1; o < 64; o <<= 1) {
        int u = __shfl_up(inc, o);
        if (lane >= o) inc += u;
    }
    __shared__ int wsum[4];
    if (lane == 63) wsum[wid] = inc;
    __syncthreads();
    int woff = 0;
    for (int i = 0; i < wid; ++i) woff += wsum[i];
    int excl = inc - s + woff + boff[blockIdx.x];
#pragma unroll
    for (int k = 0; k < PT; ++k) {
        int id = idx0 + k;
        if (id < n) out1[id] = excl;
        excl += vals[k];
    }
    if (blockIdx.x == 0 && threadIdx.x == 0) out1[n] = total;
}

// ---------------- CSR build: counting sort, all-LDS atomics ----------------

// A1: per-(bucket,block) histogram only — NO global atomics
__global__ LB256 void hist_kernel(const int* __restrict__ row, int E, int nb, int chunk,
                                  int* __restrict__ countmat) {
    __shared__ int lh[512];
    for (int b = threadIdx.x; b < nb; b += 256) lh[b] = 0;
    __syncthreads();
    int beg = blockIdx.x * chunk;
    int end = min(E, beg + chunk);
    for (int i = beg + threadIdx.x; i < end; i += 256)
        atomicAdd(&lh[row[i] >> NB_SHIFT], 1);
    __syncthreads();
    for (int b = threadIdx.x; b < nb; b += 256)
        countmat[b * gridDim.x + blockIdx.x] = lh[b];
}

// A2: deterministic scatter into bucket-ordered tmp. entry = (col | rowlocal<<17, w)
__global__ LB256 void bucket_scatter_kernel(const int* __restrict__ row, const int* __restrict__ col,
                                            const float* __restrict__ w, const int* __restrict__ off,
                                            int E, int nb, int chunk, float2* __restrict__ tmp) {
    __shared__ int lc[512];
    __shared__ int loff[512];
    for (int b = threadIdx.x; b < nb; b += 256) {
        lc[b] = 0;
        loff[b] = off[b * gridDim.x + blockIdx.x];
    }
    __syncthreads();
    int beg = blockIdx.x * chunk;
    int end = min(E, beg + chunk);
    for (int i = beg + threadIdx.x; i < end; i += 256) {
        int r = row[i];
        int b = r >> NB_SHIFT;
        int lpos = atomicAdd(&lc[b], 1);
        unsigned pk = (unsigned)col[i] | ((unsigned)(r & (NB_ROWS - 1)) << 17);
        tmp[loff[b] + lpos] = make_float2(__int_as_float((int)pk), w[i]);
    }
}

// B (fused): one block per bucket. LDS histogram of rowlocal -> block scan ->
// rowptr write + LDS-cursor scatter tmp->csr. NO global atomics.
__global__ LB256 void csr_build_kernel(const float2* __restrict__ tmp, const int* __restrict__ off,
                                       int G, int N, int E,
                                       int* __restrict__ rowptr, float2* __restrict__ csr) {
    __shared__ int lcnt[NB_ROWS];
    __shared__ int lex[NB_ROWS];
    __shared__ int wsum[4];
    int b = blockIdx.x;
    int tid = threadIdx.x;
    int s0 = off[b * G];
    int e0 = off[(b + 1) * G];   // last bucket: off[M] = E
    int rbase = b << NB_SHIFT;

    lcnt[tid] = 0;
    __syncthreads();
    for (int j = s0 + tid; j < e0; j += 256) {
        unsigned p = (unsigned)__float_as_int(tmp[j].x);
        atomicAdd(&lcnt[p >> 17], 1);
    }
    __syncthreads();

    // block-exclusive-scan of 256 counters
    int v = lcnt[tid];
    int lane = tid & 63, wid = tid >> 6;
    int inc = v;
#pragma unroll
    for (int o = 1; o < 64; o <<= 1) {
        int u = __shfl_up(inc, o);
        if (lane >= o) inc += u;
    }
    if (lane == 63) wsum[wid] = inc;
    __syncthreads();
    int woff = 0;
    for (int i = 0; i < wid; ++i) woff += wsum[i];
    int ex = inc - v + woff;
    lex[tid] = ex;

    int idx = rbase + tid;
    if (idx < N) rowptr[idx] = s0 + ex;
    if (b == gridDim.x - 1 && tid == 0) rowptr[N] = E;  // sentinel (also covered when N%256!=0)
    __syncthreads();
    lcnt[tid] = ex;  // cursors
    __syncthreads();

    for (int j = s0 + tid; j < e0; j += 256) {
        float2 c = tmp[j];
        unsigned p = (unsigned)__float_as_int(c.x);
        int pos = s0 + atomicAdd(&lcnt[p >> 17], 1);
        csr[pos] = make_float2(__int_as_float((int)(p & 0x1FFFF)), c.y);
    }
}

// ---------------- per-layer kernels ----------------

template <int FIN, int FOUT>
__global__ LB256 void transform_kernel(const float* __restrict__ h, const float* __restrict__ W,
                                       float* __restrict__ t, int n) {
    int i = blockIdx.x * blockDim.x + threadIdx.x;
    if (i >= n * FOUT) return;
    int v = i / FOUT;
    int f = i % FOUT;
    float s = 0.0f;
#pragma unroll
    for (int k = 0; k < FIN; ++k) s = fmaf(h[v * FIN + k], W[f * FIN + k], s);
    t[i] = s;
}

template <int F>
__global__ LB256 void agg_kernel(const int* __restrict__ rowptr, const float2* __restrict__ csr,
                                 const float* __restrict__ t, const float* __restrict__ b,
                                 float* __restrict__ h, int n) {
    constexpr int RPB = 256 / F;
    int lane = threadIdx.x % F;
    int grp = threadIdx.x / F;
    int v = blockIdx.x * RPB + grp;
    if (v >= n) return;
    int beg = rowptr[v], end = rowptr[v + 1];
    float bf = b[lane];
    float acc0 = 0.0f, acc1 = 0.0f;
    int j = beg;
    for (; j + 1 < end; j += 2) {
        float2 cw0 = csr[j];
        float2 cw1 = csr[j + 1];
        int c0 = __float_as_int(cw0.x);
        int c1 = __float_as_int(cw1.x);
        float m0 = fmaf(cw0.y, t[c0 * F + lane], bf);
        float m1 = fmaf(cw1.y, t[c1 * F + lane], bf);
        acc0 += (m0 > 0.0f) ? m0 : 0.01f * m0;
        acc1 += (m1 > 0.0f) ? m1 : 0.01f * m1;
    }
    if (j < end) {
        float2 cw = csr[j];
        int c = __float_as_int(cw.x);
        float m = fmaf(cw.y, t[c * F + lane], bf);
        acc0 += (m > 0.0f) ? m : 0.01f * m;
    }
    int deg = end - beg;
    float inv = (deg > 0) ? (1.0f / (float)deg) : 0.0f;
    float r = t[v * F + lane] + bf;
    r = (r > 0.0f) ? r : 0.01f * r;
    h[v * F + lane] = (acc0 + acc1) * inv + r;
}

// ---------------- head ----------------

__global__ LB256 void pool_kernel(const float* __restrict__ h, float* __restrict__ pool, int n) {
    __shared__ float ls[256];
    int f = threadIdx.x & 31;
    int grp = threadIdx.x >> 5;
    int gid = blockIdx.x * (blockDim.x >> 5) + grp;
    int ngrp = (blockDim.x >> 5) * gridDim.x;
    float s = 0.0f;
    for (int v = gid; v < n; v += ngrp) s += h[v * 32 + f];
    ls[threadIdx.x] = s;
    __syncthreads();
    if (threadIdx.x < 32) {
        float tot = 0.0f;
#pragma unroll
        for (int g = 0; g < 8; ++g) tot += ls[g * 32 + threadIdx.x];
        atomicAdd(&pool[threadIdx.x], tot);
    }
}

__global__ void head_kernel(const float* __restrict__ pool, const float* __restrict__ W7,
                            const float* __restrict__ b7, float* __restrict__ out, int n) {
    if (threadIdx.x != 0 || blockIdx.x != 0) return;
    float invn = 1.0f / (float)n;
    float l0 = b7[0], l1 = b7[1];
    for (int f = 0; f < 32; ++f) {
        float p = pool[f] * invn;
        l0 = fmaf(p, W7[f], l0);
        l1 = fmaf(p, W7[32 + f], l1);
    }
    float m = fmaxf(l0, l1);
    float lse = m + logf(expf(l0 - m) + expf(l1 - m));
    out[0] = l0 - lse;
    out[1] = l1 - lse;
}

// ---------------- launch ----------------

extern "C" void kernel_launch(void* const* d_in, const int* in_sizes, int n_in,
                              void* d_out, int out_size, void* d_ws, size_t ws_size,
                              hipStream_t stream) {
    const float* x  = (const float*)d_in[0];
    const int* edge = (const int*)d_in[1];
    const float* w  = (const float*)d_in[2];
    const float* W1 = (const float*)d_in[3];
    const float* b1 = (const float*)d_in[4];
    const float* W3 = (const float*)d_in[5];
    const float* b3 = (const float*)d_in[6];
    const float* W5 = (const float*)d_in[7];
    const float* b5 = (const float*)d_in[8];
    const float* W7 = (const float*)d_in[9];
    const float* b7 = (const float*)d_in[10];
    float* out = (float*)d_out;

    const int N = in_sizes[0] / 4;
    const int E = in_sizes[1] / 2;
    const int* row = edge;
    const int* col = edge + E;

    const int nb = (N + NB_ROWS - 1) >> NB_SHIFT;    // 391 buckets
    const int G = GA;
    const int chunk = (E + G - 1) / G;
    const int M = nb * G;                            // ~200k

    char* ws = (char*)d_ws;
    size_t off8 = 0;
    auto alloc = [&](size_t bytes) {
        void* p = ws + off8;
        off8 += (bytes + 255) & ~(size_t)255;
        return p;
    };
    int*    rowptr   = (int*)alloc(((size_t)N + 1) * 4);
    int*    bsumB    = (int*)alloc(256 * 4);
    int*    boffB    = (int*)alloc(256 * 4);
    int*    countmat = (int*)alloc((size_t)M * 4);
    int*    offm     = (int*)alloc(((size_t)M + 1) * 4);
    float*  pool     = (float*)alloc(32 * 4);
    float2* csr      = (float2*)alloc((size_t)E * 8);
    size_t bigsz = (size_t)E * 8;
    size_t thsz  = (size_t)N * 32 * 4 * 2;
    char*  big   = (char*)alloc(bigsz > thsz ? bigsz : thsz);
    float2* tmp  = (float2*)big;
    float*  t    = (float*)big;
    float*  h    = (float*)(big + (size_t)N * 32 * 4);
    (void)ws_size;

    hipMemsetAsync(pool, 0, 32 * 4, stream);

    const int B = 256;
    const int nbkM = (M + 4095) / 4096;       // <= 64

    // CSR build (no global atomics anywhere)
    hist_kernel<<<G, B, 0, stream>>>(row, E, nb, chunk, countmat);
    gscan_sum<16><<<nbkM, B, 0, stream>>>(countmat, M, bsumB);
    gscan_offsets<<<1, 64, 0, stream>>>(bsumB, nbkM, boffB);
    gscan_scatter<16><<<nbkM, B, 0, stream>>>(countmat, M, boffB, E, offm);
    bucket_scatter_kernel<<<G, B, 0, stream>>>(row, col, w, offm, E, nb, chunk, tmp);
    csr_build_kernel<<<nb, B, 0, stream>>>(tmp, offm, G, N, E, rowptr, csr);

    // ---- block 1: 4 -> 8 ----
    transform_kernel<4, 8><<<(N * 8 + B - 1) / B, B, 0, stream>>>(x, W1, t, N);
    agg_kernel<8><<<(N + 31) / 32, B, 0, stream>>>(rowptr, csr, t, b1, h, N);

    // ---- block 2: 8 -> 16 ----
    transform_kernel<8, 16><<<(N * 16 + B - 1) / B, B, 0, stream>>>(h, W3, t, N);
    agg_kernel<16><<<(N + 15) / 16, B, 0, stream>>>(rowptr, csr, t, b3, h, N);

    // ---- block 3: 16 -> 32 ----
    transform_kernel<16, 32><<<(N * 32 + B - 1) / B, B, 0, stream>>>(h, W5, t, N);
    agg_kernel<32><<<(N + 7) / 8, B, 0, stream>>>(rowptr, csr, t, b5, h, N);

    // ---- head ----
    pool_kernel<<<256, B, 0, stream>>>(h, pool, N);
    head_kernel<<<1, 64, 0, stream>>>(pool, W7, b7, out, N);
}